// Round 5
// baseline (715.299 us; speedup 1.0000x reference)
//
#include <hip/hip_runtime.h>

// LIF multi-compartment refractory cell step. B=4096, H=I=2048, fp32 in/out.
//
// Round 9:
//  R8 post-mortem: depth-2 at 128^2 regressed via occupancy (3 blocks/CU max vs
//  4-block demand -> straggler tail). R7's 331 TF = m97-structure shape-curve
//  ceiling at 2048-class shapes (m102: 320 TF). Structural port instead:
//  - k_gemm256: BM=256 x BN=128, BK=64, 512 thr (8 waves 4Mx2N), 3-buffer
//    depth-2 pipeline with R8's proven 2-barrier/K-step sync skeleton,
//    counted vmcnt(12)/(6)/(0). 256 persistent blocks = 1/CU; each block does
//    role0 tile (32 kt) then role1 tile (64 kt) = 96 uniform K-steps -> no
//    role imbalance, no tail. 32 MFMA/wave/barrier (2x R7).
//  - LDS flag aggregation, 4x2 XCD tiling, k_cast, k_fixup from R7.
//  - Legacy 128^2 float kernel retained only for the (never-taken) !use16 path.

#define HDIM 2048
#define BATCH 4096
#define KIN 2048
#define MARGIN 0.02f
#define FLAG_LDS_CAP 512

// new-kernel geometry
#define BM2 256
#define BN2 128
#define BK2 64
#define NTHR 512

// legacy fallback geometry
#define BM 128
#define BN 128
#define BK 32

typedef _Float16 f16x8 __attribute__((ext_vector_type(8)));
typedef __fp16 h16x2 __attribute__((ext_vector_type(2)));   // cvt_pkrtz return type
typedef float f32x4 __attribute__((ext_vector_type(4)));

// ==================== new 256x128 f16 kernel ====================

// staging: global -> LDS via 16B DMA, lane-contiguous LDS, XOR-swizzled source.
// BK2=64 f16 -> 8 chunks of 16B per row; swizzle c = cs ^ (r&7).
template <int ROWS>
__device__ __forceinline__ void stage2(const _Float16* src, int row0, int k0,
                                       _Float16* lds_tile, int t) {
  constexpr int CHN = (BK2 * 2) / 16;  // 8
#pragma unroll
  for (int j = 0; j < (ROWS * CHN) / NTHR; ++j) {
    const int u = j * NTHR + t;                    // LDS chunk slot (lane-contiguous)
    const int r = u / CHN;
    const int cs = u & (CHN - 1);
    const int c = cs ^ (r & (CHN - 1));
    const _Float16* g = src + (size_t)(row0 + r) * KIN + k0 + c * 8;
    __builtin_amdgcn_global_load_lds(
        (const __attribute__((address_space(1))) void*)g,
        (__attribute__((address_space(3))) void*)(lds_tile + u * 8), 16, 0, 0);
  }
}

// fragment reader (undo swizzle): row r, 16B-chunk c (= ks*4 + quad)
__device__ __forceinline__ f16x8 read_frag2(const _Float16* tile, int r, int c) {
  const int slot = r * 8 + (c ^ (r & 7));
  return *(const f16x8*)(tile + slot * 8);
}

__global__ __launch_bounds__(NTHR, 2)
void k_gemm256(const _Float16* vA, const _Float16* inpA, const _Float16* zA,
               const _Float16* gB, const _Float16* WiB, const _Float16* WrB,
               const float* v, const float* cur_in, const float* rho,
               float* z_out, float* v_out, float* rho_out, float* i_out,
               unsigned* flag_cnt, unsigned* flag_list, unsigned flag_cap) {
  __shared__ _Float16 As[3][BM2 * BK2];   // 3 x 32 KB
  __shared__ _Float16 Bs[3][BN2 * BK2];   // 3 x 16 KB
  __shared__ unsigned s_cnt, s_base;
  __shared__ unsigned s_idx[FLAG_LDS_CAP];
  const int t = threadIdx.x;
  const int bid = blockIdx.x;             // 256 blocks, 1 per CU (144KB LDS)
  // XCD-aware 4x2 grid over (M,N); 32 blocks per XCD = 4 M-tiles x 8 N-tiles
  const int x = bid & 7;                  // XCD
  const int jj = bid >> 3;                // 0..31 within XCD
  const int mg = x & 3, ng = x >> 2;
  const int m0 = (mg * 4 + (jj >> 3)) * BM2;   // 16 M-tiles of 256
  const int n0 = (ng * 8 + (jj & 7)) * BN2;    // 16 N-tiles of 128

  const int wave = t >> 6, lane = t & 63;
  const int wm = (wave >> 1) * 64, wn = (wave & 1) * 64;  // 4M x 2N waves
  const int lrow = lane & 15, quad = lane >> 4;
  if (t == 0) s_cnt = 0;                  // visible after first K-loop barrier

  for (int job = 0; job < 2; ++job) {
    const int role = job;                 // job0: v@g^T; job1: inp@Wi^T + z@Wr^T
    const int NT = role ? (2 * KIN) / BK2 : KIN / BK2;  // 64 : 32

    auto pick = [&](int k0, const _Float16*& Ap, const _Float16*& Bp) {
      if (role == 0)     { Ap = vA;   Bp = gB;  }
      else if (k0 < KIN) { Ap = inpA; Bp = WiB; }
      else               { Ap = zA;   Bp = WrB; }
    };

    // prologue: tiles 0,1 -> buffers 0,1 (12 gll in flight per wave)
    {
      const _Float16 *Ap, *Bp;
      pick(0, Ap, Bp);
      stage2<BM2>(Ap, m0, 0, As[0], t);
      stage2<BN2>(Bp, n0, 0, Bs[0], t);
      pick(BK2, Ap, Bp);
      stage2<BM2>(Ap, m0, BK2, As[1], t);
      stage2<BN2>(Bp, n0, BK2, Bs[1], t);
    }

    f32x4 acc[4][4] = {};
    int cur = 0;                          // = it % 3
    for (int it = 0; it < NT; ++it) {
      const int nxt = it + 2;
      if (nxt < NT) {
        // issue tile it+2 into (cur+2)%3; its readers finished at the trailing
        // barrier of iteration it-1, which this wave has passed
        const _Float16 *Ap, *Bp;
        pick(nxt * BK2, Ap, Bp);
        const int kl = (nxt * BK2) & (KIN - 1);
        const int buf = (cur >= 1) ? cur - 1 : 2;
        stage2<BM2>(Ap, m0, kl, As[buf], t);
        stage2<BN2>(Bp, n0, kl, Bs[buf], t);
        // 18 gll outstanding (t,t+1,t+2 x 6); drain tile it's 6
        asm volatile("s_waitcnt vmcnt(12)" ::: "memory");
      } else if (it + 1 < NT) {
        asm volatile("s_waitcnt vmcnt(6)" ::: "memory");
      } else {
        asm volatile("s_waitcnt vmcnt(0)" ::: "memory");
      }
      __builtin_amdgcn_s_barrier();       // tile-it data in LDS for all waves
      asm volatile("" ::: "memory");

      f16x8 af[2][4], bf[2][4];
#pragma unroll
      for (int ks = 0; ks < 2; ++ks) {
#pragma unroll
        for (int mi = 0; mi < 4; ++mi)
          af[ks][mi] = read_frag2(As[cur], wm + mi * 16 + lrow, ks * 4 + quad);
#pragma unroll
        for (int ni = 0; ni < 4; ++ni)
          bf[ks][ni] = read_frag2(Bs[cur], wn + ni * 16 + lrow, ks * 4 + quad);
      }
#pragma unroll
      for (int ks = 0; ks < 2; ++ks)
#pragma unroll
        for (int mi = 0; mi < 4; ++mi)
#pragma unroll
          for (int ni = 0; ni < 4; ++ni)
            acc[mi][ni] = __builtin_amdgcn_mfma_f32_16x16x32_f16(
                af[ks][mi], bf[ks][ni], acc[mi][ni], 0, 0, 0);

      asm volatile("" ::: "memory");
      __builtin_amdgcn_s_barrier();       // buf[cur] free for overwrite at it+1
      cur = (cur == 2) ? 0 : cur + 1;
    }

    // C/D layout: col = lane&15, row = quad*4 + reg
    if (role == 0) {
#pragma unroll
      for (int mi = 0; mi < 4; ++mi)
#pragma unroll
        for (int r = 0; r < 4; ++r) {
          const int row = m0 + wm + mi * 16 + quad * 4 + r;
#pragma unroll
          for (int ni = 0; ni < 4; ++ni) {
            const int col = n0 + wn + ni * 16 + lrow;
            const size_t idx = (size_t)row * HDIM + col;
            const float P = acc[mi][ni][r];
            const float vv = v[idx], ii = cur_in[idx], rr = rho[idx];
            const float vd = vv + 0.1f * (ii - vv) + P;
            float zo, vo, ro;
            if (rr > 0.0f) {  // refractory: hold v, suppress spike
              zo = 0.0f; vo = vv; ro = fmaxf(rr - 1.0f, 0.0f);
            } else {
              const bool zs = vd > 1.0f;
              zo = zs ? 1.0f : 0.0f;
              vo = zs ? 0.0f : vd;
              ro = zs ? 5.0f : fmaxf(rr, 0.0f);
              if (fabsf(vd - 1.0f) < MARGIN) {
                unsigned p = atomicAdd(&s_cnt, 1u);   // block-local aggregation
                if (p < FLAG_LDS_CAP) s_idx[p] = (unsigned)idx;
                else {
                  unsigned q = atomicAdd(flag_cnt, 1u);
                  if (q < flag_cap) flag_list[q] = (unsigned)idx;
                }
              }
            }
            z_out[idx] = zo; v_out[idx] = vo; rho_out[idx] = ro;
          }
        }
      __syncthreads();                    // all flags in LDS
      unsigned n = s_cnt;
      if (n > FLAG_LDS_CAP) n = FLAG_LDS_CAP;
      if (t == 0) s_base = atomicAdd(flag_cnt, n);  // ONE global atomic per block
      __syncthreads();
      for (unsigned u = t; u < n; u += NTHR) {
        const unsigned d = s_base + u;
        if (d < flag_cap) flag_list[d] = s_idx[u];  // coalesced copy
      }
    } else {
#pragma unroll
      for (int mi = 0; mi < 4; ++mi)
#pragma unroll
        for (int r = 0; r < 4; ++r) {
          const int row = m0 + wm + mi * 16 + quad * 4 + r;
#pragma unroll
          for (int ni = 0; ni < 4; ++ni) {
            const int col = n0 + wn + ni * 16 + lrow;
            const size_t idx = (size_t)row * HDIM + col;
            const float ii = cur_in[idx];
            i_out[idx] = (ii - 0.2f * ii) + acc[mi][ni][r];
          }
        }
    }
  }
}

// ==================== legacy 128^2 kernel (f32 fallback only) ====================

template <typename T>
__device__ __forceinline__ void stage(const T* src, int ldk, int row0, int k0,
                                      T* lds_tile, int t) {
  constexpr int CHN = (BK * (int)sizeof(T)) / 16;
  constexpr int EPC = 16 / (int)sizeof(T);
#pragma unroll
  for (int j = 0; j < (BM * CHN) / 256; ++j) {
    const int u = j * 256 + t;
    const int r = u / CHN;
    const int cs = u & (CHN - 1);
    const int c = cs ^ (((r * CHN) >> 3) & (CHN - 1));
    const T* g = src + (size_t)(row0 + r) * ldk + k0 + c * EPC;
    __builtin_amdgcn_global_load_lds(
        (const __attribute__((address_space(1))) void*)(T*)g,
        (__attribute__((address_space(3))) void*)(lds_tile + u * EPC), 16, 0, 0);
  }
}

__device__ __forceinline__ f16x8 read_frag(const float* tile, int r, int q) {
  const int s = r & 7;
  const f32x4 a = *(const f32x4*)(tile + (r * 8 + ((2 * q) ^ s)) * 4);
  const f32x4 b = *(const f32x4*)(tile + (r * 8 + ((2 * q + 1) ^ s)) * 4);
  f16x8 o;
  h16x2 p;
  p = __builtin_amdgcn_cvt_pkrtz(a[0], a[1]); o[0] = (_Float16)p[0]; o[1] = (_Float16)p[1];
  p = __builtin_amdgcn_cvt_pkrtz(a[2], a[3]); o[2] = (_Float16)p[0]; o[3] = (_Float16)p[1];
  p = __builtin_amdgcn_cvt_pkrtz(b[0], b[1]); o[4] = (_Float16)p[0]; o[5] = (_Float16)p[1];
  p = __builtin_amdgcn_cvt_pkrtz(b[2], b[3]); o[6] = (_Float16)p[0]; o[7] = (_Float16)p[1];
  return o;
}

__global__ __launch_bounds__(256, 4)
void k_gemm128f(const float* vA, const float* inpA, const float* zA,
                const float* gB, const float* WiB, const float* WrB,
                const float* v, const float* cur_in, const float* rho,
                float* z_out, float* v_out, float* rho_out, float* i_out,
                unsigned* flag_cnt, unsigned* flag_list, unsigned flag_cap) {
  __shared__ float As[2][BM * BK];
  __shared__ float Bs[2][BN * BK];
  const int t = threadIdx.x;
  const int bid = blockIdx.x;
  const int x = bid & 7;
  const int j = bid >> 3;
  const int role = (j >> 5) & 1;
  const int jj = (j & 31) | ((j >> 6) << 5);
  const int mg = x & 3, ng = x >> 2;
  const int m0 = (mg * 8 + (jj >> 3)) * BM;
  const int n0 = (ng * 8 + (jj & 7)) * BN;

  const int wave = t >> 6, lane = t & 63;
  const int wm = (wave >> 1) * 64, wn = (wave & 1) * 64;
  const int lrow = lane & 15, quad = lane >> 4;

  const int kmax = role ? 2 * KIN : KIN;
  const int NT = kmax / BK;

  auto pick = [&](int k0, const float*& Ap, const float*& Bp) {
    if (role == 0)      { Ap = vA;   Bp = gB;  }
    else if (k0 < KIN)  { Ap = inpA; Bp = WiB; }
    else                { Ap = zA;   Bp = WrB; }
  };
  {
    const float *Ap, *Bp;
    pick(0, Ap, Bp);
    stage(Ap, KIN, m0, 0, As[0], t);
    stage(Bp, KIN, n0, 0, Bs[0], t);
  }
  f32x4 acc[4][4] = {};
#pragma unroll 2
  for (int it = 0; it < NT; ++it) {
    const int cur = it & 1;
    if (it + 1 < NT) {
      const float *Ap, *Bp;
      pick((it + 1) * BK, Ap, Bp);
      const int kl = ((it + 1) * BK) & (KIN - 1);
      stage(Ap, KIN, m0, kl, As[cur ^ 1], t);
      stage(Bp, KIN, n0, kl, Bs[cur ^ 1], t);
      asm volatile("s_waitcnt vmcnt(8)" ::: "memory");
    } else {
      asm volatile("s_waitcnt vmcnt(0)" ::: "memory");
    }
    __builtin_amdgcn_s_barrier();
    asm volatile("" ::: "memory");
    f16x8 af[4], bf[4];
#pragma unroll
    for (int mi = 0; mi < 4; ++mi) af[mi] = read_frag(As[cur], wm + mi * 16 + lrow, quad);
#pragma unroll
    for (int ni = 0; ni < 4; ++ni) bf[ni] = read_frag(Bs[cur], wn + ni * 16 + lrow, quad);
#pragma unroll
    for (int mi = 0; mi < 4; ++mi)
#pragma unroll
      for (int ni = 0; ni < 4; ++ni)
        acc[mi][ni] =
            __builtin_amdgcn_mfma_f32_16x16x32_f16(af[mi], bf[ni], acc[mi][ni], 0, 0, 0);
    asm volatile("" ::: "memory");
    __builtin_amdgcn_s_barrier();
  }

  if (role == 0) {
#pragma unroll
    for (int mi = 0; mi < 4; ++mi)
#pragma unroll
      for (int r = 0; r < 4; ++r) {
        const int row = m0 + wm + mi * 16 + quad * 4 + r;
#pragma unroll
        for (int ni = 0; ni < 4; ++ni) {
          const int col = n0 + wn + ni * 16 + lrow;
          const size_t idx = (size_t)row * HDIM + col;
          const float P = acc[mi][ni][r];
          const float vv = v[idx], ii = cur_in[idx], rr = rho[idx];
          const float vd = vv + 0.1f * (ii - vv) + P;
          float zo, vo, ro;
          if (rr > 0.0f) { zo = 0.0f; vo = vv; ro = fmaxf(rr - 1.0f, 0.0f); }
          else {
            const bool zs = vd > 1.0f;
            zo = zs ? 1.0f : 0.0f;
            vo = zs ? 0.0f : vd;
            ro = zs ? 5.0f : fmaxf(rr, 0.0f);
            if (fabsf(vd - 1.0f) < MARGIN) {
              unsigned p = atomicAdd(flag_cnt, 1u);
              if (p < flag_cap) flag_list[p] = (unsigned)idx;
            }
          }
          z_out[idx] = zo; v_out[idx] = vo; rho_out[idx] = ro;
        }
      }
  } else {
#pragma unroll
    for (int mi = 0; mi < 4; ++mi)
#pragma unroll
      for (int r = 0; r < 4; ++r) {
        const int row = m0 + wm + mi * 16 + quad * 4 + r;
#pragma unroll
        for (int ni = 0; ni < 4; ++ni) {
          const int col = n0 + wn + ni * 16 + lrow;
          const size_t idx = (size_t)row * HDIM + col;
          const float ii = cur_in[idx];
          i_out[idx] = (ii - 0.2f * ii) + acc[mi][ni][r];
        }
      }
  }
}

// ---- fp32 -> f16 cast of all six GEMM operands into ws; zero flag counter --------
__global__ void k_cast(const float* __restrict__ v, const float* __restrict__ inp,
                       const float* __restrict__ z, const float* __restrict__ g,
                       const float* __restrict__ Wi, const float* __restrict__ Wr,
                       _Float16* __restrict__ dst, unsigned* __restrict__ flag_cnt) {
  if (blockIdx.x == 0 && threadIdx.x == 0) *flag_cnt = 0;
  const size_t NA = (size_t)BATCH * HDIM, NB = (size_t)HDIM * HDIM;
  const size_t TOT = (3 * NA + 3 * NB) / 8;
  const size_t w = (size_t)blockIdx.x * blockDim.x + threadIdx.x;
  if (w >= TOT) return;
  const size_t e = w * 8;
  const float* s; size_t off;
  if      (e < NA)          { s = v;   off = e; }
  else if (e < 2 * NA)      { s = inp; off = e - NA; }
  else if (e < 3 * NA)      { s = z;   off = e - 2 * NA; }
  else if (e < 3 * NA + NB) { s = g;   off = e - 3 * NA; }
  else if (e < 3 * NA + 2 * NB) { s = Wi; off = e - 3 * NA - NB; }
  else                      { s = Wr;  off = e - 3 * NA - 2 * NB; }
  const f32x4 a = *(const f32x4*)(s + off);
  const f32x4 b = *(const f32x4*)(s + off + 4);
  f16x8 o; h16x2 p;
  p = __builtin_amdgcn_cvt_pkrtz(a[0], a[1]); o[0] = (_Float16)p[0]; o[1] = (_Float16)p[1];
  p = __builtin_amdgcn_cvt_pkrtz(a[2], a[3]); o[2] = (_Float16)p[0]; o[3] = (_Float16)p[1];
  p = __builtin_amdgcn_cvt_pkrtz(b[0], b[1]); o[4] = (_Float16)p[0]; o[5] = (_Float16)p[1];
  p = __builtin_amdgcn_cvt_pkrtz(b[2], b[3]); o[6] = (_Float16)p[0]; o[7] = (_Float16)p[1];
  *(f16x8*)(dst + e) = o;
}

__global__ void k_zero_cnt(unsigned* p) { if (threadIdx.x == 0) p[0] = 0; }

// ---- fp64 exact recompute of near-threshold neurons ------------------------------
__global__ __launch_bounds__(256, 2)
void k_fixup(const float* __restrict__ v, const float* __restrict__ cur,
             const float* __restrict__ rho, const float* __restrict__ g,
             float* __restrict__ z_out, float* __restrict__ v_out,
             float* __restrict__ rho_out,
             const unsigned* __restrict__ flag_cnt,
             const unsigned* __restrict__ flag_list, unsigned flag_cap) {
  unsigned n = *flag_cnt;
  if (n > flag_cap) n = flag_cap;
  const int lane = threadIdx.x & 63;
  const int nw = gridDim.x * 4;
  for (unsigned it = blockIdx.x * 4 + (threadIdx.x >> 6); it < n; it += nw) {
    const unsigned idx = flag_list[it];
    const unsigned b = idx >> 11, h = idx & (HDIM - 1);
    const float* vp = v + (size_t)b * HDIM;
    const float* gp = g + (size_t)h * HDIM;
    double s0 = 0.0, s1 = 0.0, s2 = 0.0, s3 = 0.0;
    for (int k = lane; k < KIN; k += 256) {
      s0 += (double)vp[k]       * (double)gp[k];
      s1 += (double)vp[k + 64]  * (double)gp[k + 64];
      s2 += (double)vp[k + 128] * (double)gp[k + 128];
      s3 += (double)vp[k + 192] * (double)gp[k + 192];
    }
    double s = (s0 + s1) + (s2 + s3);
#pragma unroll
    for (int off = 32; off; off >>= 1) s += __shfl_down(s, off, 64);
    if (lane == 0) {
      const double vv = (double)v[idx], ii = (double)cur[idx];
      const double vd = (vv + (0.001 * 100.0) * ((0.0 - vv) + ii)) + s;
      const bool zs = vd > 1.0;
      z_out[idx]   = zs ? 1.0f : 0.0f;
      v_out[idx]   = zs ? 0.0f : (float)vd;
      rho_out[idx] = zs ? 5.0f : fmaxf(rho[idx], 0.0f);
    }
  }
}

extern "C" void kernel_launch(void* const* d_in, const int* in_sizes, int n_in,
                              void* d_out, int out_size, void* d_ws, size_t ws_size,
                              hipStream_t stream) {
  (void)in_sizes; (void)n_in; (void)out_size;
  const float* inp = (const float*)d_in[0];
  const float* z   = (const float*)d_in[1];
  const float* v   = (const float*)d_in[2];
  const float* cur = (const float*)d_in[3];
  const float* rho = (const float*)d_in[4];
  const float* Wi  = (const float*)d_in[5];
  const float* Wr  = (const float*)d_in[6];
  const float* g   = (const float*)d_in[7];

  float* out = (float*)d_out;
  const size_t NE = (size_t)BATCH * HDIM;
  float* z_out = out;
  float* v_out = out + NE;
  float* i_out = out + 2 * NE;
  float* rho_out = out + 3 * NE;

  const size_t NA = NE, NB = (size_t)HDIM * HDIM;
  const size_t F16_NEED = (3 * NA + 3 * NB) * sizeof(_Float16);  // ~72 MB
  const bool use16 = ws_size >= F16_NEED + (1u << 22);

  unsigned* flag_cnt =
      use16 ? (unsigned*)((char*)d_ws + F16_NEED) : (unsigned*)d_ws;
  unsigned* flag_list = flag_cnt + 4;
  unsigned flag_cap = 0;
  {
    const size_t used = (size_t)((char*)flag_list - (char*)d_ws);
    if (ws_size > used + 64) {
      size_t cap = (ws_size - used) / sizeof(unsigned);
      if (cap > (size_t)4 * 1024 * 1024) cap = (size_t)4 * 1024 * 1024;
      flag_cap = (unsigned)cap;
    }
  }

  if (use16) {
    _Float16* ws16 = (_Float16*)d_ws;
    const _Float16* vh   = ws16;
    const _Float16* inph = ws16 + NA;
    const _Float16* zh   = ws16 + 2 * NA;
    const _Float16* gh   = ws16 + 3 * NA;
    const _Float16* Wih  = ws16 + 3 * NA + NB;
    const _Float16* Wrh  = ws16 + 3 * NA + 2 * NB;
    const size_t TOT = (3 * NA + 3 * NB) / 8;
    k_cast<<<(unsigned)((TOT + 255) / 256), 256, 0, stream>>>(v, inp, z, g, Wi, Wr,
                                                              ws16, flag_cnt);
    k_gemm256<<<256, NTHR, 0, stream>>>(vh, inph, zh, gh, Wih, Wrh,
                                        v, cur, rho, z_out, v_out, rho_out, i_out,
                                        flag_cnt, flag_list, flag_cap);
  } else {
    k_zero_cnt<<<1, 64, 0, stream>>>(flag_cnt);
    k_gemm128f<<<1024, 256, 0, stream>>>(v, inp, z, g, Wi, Wr,
                                         v, cur, rho, z_out, v_out, rho_out, i_out,
                                         flag_cnt, flag_list, flag_cap);
  }

  k_fixup<<<1024, 256, 0, stream>>>(v, cur, rho, g, z_out, v_out, rho_out,
                                    flag_cnt, flag_list, flag_cap);
}

// Round 6
// 597.289 us; speedup vs baseline: 1.1976x; 1.1976x over previous
//
#include <hip/hip_runtime.h>

// LIF multi-compartment refractory cell step. B=4096, H=I=2048, fp32 in/out.
//
// Round 10:
//  R8/R9 post-mortem: depth-2 and 256x128 both regressed (311 -> 368 / 384 us).
//  Perf tracks co-resident blocks; R7's 331 TF = this structure's shape ceiling
//  (m102: 320 TF @2048). GEMM loop reverted to R7 EXACTLY (proven 311 us).
//  This round attacks the non-GEMM 311 us: k_fixup (~40k flags x 16KB v/g row
//  reads ~ 150-250 us serialized dispatch) is folded INTO k_gemm's role-0
//  blocks: they finish their 64 K-steps at half-time (role-1 runs 128) and
//  process their own LDS flag list while role-1 blocks still compute -> fixup
//  hides in the role-imbalance slack. Global flag list = overflow-only;
//  k_fixup becomes a ~5us sweep (grid 64). Numerics identical (same fp64 dot,
//  same reduce order).

#define HDIM 2048
#define BATCH 4096
#define KIN 2048
#define BM 128
#define BN 128
#define BK 32
#define MARGIN 0.02f
#define FLAG_LDS_CAP 512

typedef _Float16 f16x8 __attribute__((ext_vector_type(8)));
typedef __fp16 h16x2 __attribute__((ext_vector_type(2)));   // cvt_pkrtz return type
typedef float f32x4 __attribute__((ext_vector_type(4)));

// ---- staging: global -> LDS via 16B DMA, lane-contiguous LDS, XOR-swizzled source --
template <typename T>
__device__ __forceinline__ void stage(const T* src, int ldk, int row0, int k0,
                                      T* lds_tile, int t) {
  constexpr int CHN = (BK * (int)sizeof(T)) / 16;  // 16B chunks per row (4 f16 / 8 f32)
  constexpr int EPC = 16 / (int)sizeof(T);         // elements per chunk
#pragma unroll
  for (int j = 0; j < (BM * CHN) / 256; ++j) {
    const int u = j * 256 + t;                     // LDS chunk slot (lane-contiguous)
    const int r = u / CHN;
    const int cs = u & (CHN - 1);
    const int c = cs ^ (((r * CHN) >> 3) & (CHN - 1));  // swizzle: f16 (r>>1)&3, f32 r&7
    const T* g = src + (size_t)(row0 + r) * ldk + k0 + c * EPC;
    __builtin_amdgcn_global_load_lds(
        (const __attribute__((address_space(1))) void*)(T*)g,
        (__attribute__((address_space(3))) void*)(lds_tile + u * EPC), 16, 0, 0);
  }
}

// ---- fragment readers (undo the swizzle) ------------------------------------------
__device__ __forceinline__ f16x8 read_frag(const _Float16* tile, int r, int q) {
  const int slot = r * 4 + (q ^ ((r >> 1) & 3));
  return *(const f16x8*)(tile + slot * 8);
}
__device__ __forceinline__ f16x8 read_frag(const float* tile, int r, int q) {
  const int s = r & 7;
  const f32x4 a = *(const f32x4*)(tile + (r * 8 + ((2 * q) ^ s)) * 4);
  const f32x4 b = *(const f32x4*)(tile + (r * 8 + ((2 * q + 1) ^ s)) * 4);
  f16x8 o;
  h16x2 p;
  p = __builtin_amdgcn_cvt_pkrtz(a[0], a[1]); o[0] = (_Float16)p[0]; o[1] = (_Float16)p[1];
  p = __builtin_amdgcn_cvt_pkrtz(a[2], a[3]); o[2] = (_Float16)p[0]; o[3] = (_Float16)p[1];
  p = __builtin_amdgcn_cvt_pkrtz(b[0], b[1]); o[4] = (_Float16)p[0]; o[5] = (_Float16)p[1];
  p = __builtin_amdgcn_cvt_pkrtz(b[2], b[3]); o[6] = (_Float16)p[0]; o[7] = (_Float16)p[1];
  return o;
}

// ---- fp64 exact recompute of one flagged neuron (64 lanes of one wave) ------------
// Identical arithmetic/reduce order to the standalone k_fixup.
__device__ __forceinline__ void fixup_one(unsigned idx, const float* __restrict__ v,
                                          const float* __restrict__ cur,
                                          const float* __restrict__ rho,
                                          const float* __restrict__ g,
                                          float* __restrict__ z_out,
                                          float* __restrict__ v_out,
                                          float* __restrict__ rho_out, int lane) {
  const unsigned b = idx >> 11, h = idx & (HDIM - 1);
  const float* vp = v + (size_t)b * HDIM;
  const float* gp = g + (size_t)h * HDIM;
  double s0 = 0.0, s1 = 0.0, s2 = 0.0, s3 = 0.0;
  for (int k = lane; k < KIN; k += 256) {
    s0 += (double)vp[k]       * (double)gp[k];
    s1 += (double)vp[k + 64]  * (double)gp[k + 64];
    s2 += (double)vp[k + 128] * (double)gp[k + 128];
    s3 += (double)vp[k + 192] * (double)gp[k + 192];
  }
  double s = (s0 + s1) + (s2 + s3);
#pragma unroll
  for (int off = 32; off; off >>= 1) s += __shfl_down(s, off, 64);
  if (lane == 0) {
    const double vv = (double)v[idx], ii = (double)cur[idx];
    const double vd = (vv + (0.001 * 100.0) * ((0.0 - vv) + ii)) + s;
    const bool zs = vd > 1.0;
    z_out[idx]   = zs ? 1.0f : 0.0f;       // flagged elems are non-refractory
    v_out[idx]   = zs ? 0.0f : (float)vd;
    rho_out[idx] = zs ? 5.0f : fmaxf(rho[idx], 0.0f);
  }
}

// ---- fused GEMM: 2 roles, XCD-aware tile mapping, 2-phase pipeline ----------------
// Role-0 blocks additionally fix up their own near-threshold flags in-kernel
// (they finish the K-loop at half-time; the fixup hides under role-1 compute).
template <typename T>
__global__ __launch_bounds__(256, 4)
void k_gemm(const T* vA, const T* inpA, const T* zA,
            const T* gB, const T* WiB, const T* WrB,
            const float* v, const float* cur_in, const float* rho,
            float* z_out, float* v_out, float* rho_out, float* i_out,
            unsigned* flag_cnt, unsigned* flag_list, unsigned flag_cap) {
  __shared__ T As[2][BM * BK];
  __shared__ T Bs[2][BN * BK];
  __shared__ unsigned s_cnt;                 // block-local flag count
  __shared__ unsigned s_idx[FLAG_LDS_CAP];   // block-local flag list
  const int t = threadIdx.x;
  const int bid = blockIdx.x;
  // XCD-aware: round-robin dispatch puts bid%8 on XCD bid%8. 4x2 XCD grid over
  // (M,N): each XCD owns an 8-Mtile x 8-Ntile patch per role (fetch ~173MB, ideal).
  const int x = bid & 7;                     // XCD
  const int j = bid >> 3;                    // 0..127 within XCD
  const int role = (j >> 5) & 1;             // 2 role-0 + 2 role-1 per CU
  const int jj = (j & 31) | ((j >> 6) << 5); // 0..63 within role
  const int mg = x & 3, ng = x >> 2;         // 4 M-groups x 2 N-groups of XCDs
  const int m0 = (mg * 8 + (jj >> 3)) * BM;  // 32 M-tiles
  const int n0 = (ng * 8 + (jj & 7)) * BN;   // 16 N-tiles

  const int wave = t >> 6, lane = t & 63;
  const int wm = (wave >> 1) * 64, wn = (wave & 1) * 64;
  const int lrow = lane & 15, quad = lane >> 4;

  const int kmax = role ? 2 * KIN : KIN;
  const int NT = kmax / BK;

  auto pick = [&](int k0, const T*& Ap, const T*& Bp) {
    if (role == 0)      { Ap = vA;   Bp = gB;  }
    else if (k0 < KIN)  { Ap = inpA; Bp = WiB; }
    else                { Ap = zA;   Bp = WrB; }
  };

  // prologue: stage tile 0 into buffer 0 (4 gll in flight)
  {
    const T *Ap, *Bp;
    pick(0, Ap, Bp);
    stage(Ap, KIN, m0, 0, As[0], t);
    stage(Bp, KIN, n0, 0, Bs[0], t);
  }
  if (t == 0) s_cnt = 0;                     // init before first barrier

  f32x4 acc[4][4] = {};
#pragma unroll 2
  for (int it = 0; it < NT; ++it) {
    const int cur = it & 1;
    if (it + 1 < NT) {
      // issue next tile's loads into the other buffer (safe: all waves finished
      // reading it at the trailing barrier of the previous iteration)
      const int k0n = (it + 1) * BK;
      const T *Ap, *Bp;
      pick(k0n, Ap, Bp);
      const int kl = k0n & (KIN - 1);
      stage(Ap, KIN, m0, kl, As[cur ^ 1], t);
      stage(Bp, KIN, n0, kl, Bs[cur ^ 1], t);
      // wait only for buf[cur]'s 4 loads; leave the 4 just-issued in flight
      if constexpr (sizeof(T) == 2)
        asm volatile("s_waitcnt vmcnt(4)" ::: "memory");
      else
        asm volatile("s_waitcnt vmcnt(8)" ::: "memory");
    } else {
      asm volatile("s_waitcnt vmcnt(0)" ::: "memory");
    }
    __builtin_amdgcn_s_barrier();            // all waves' buf[cur] data in LDS
    asm volatile("" ::: "memory");           // fence: no LDS read hoists above

    f16x8 af[4], bf[4];
#pragma unroll
    for (int mi = 0; mi < 4; ++mi) af[mi] = read_frag(As[cur], wm + mi * 16 + lrow, quad);
#pragma unroll
    for (int ni = 0; ni < 4; ++ni) bf[ni] = read_frag(Bs[cur], wn + ni * 16 + lrow, quad);
#pragma unroll
    for (int mi = 0; mi < 4; ++mi)
#pragma unroll
      for (int ni = 0; ni < 4; ++ni)
        acc[mi][ni] =
            __builtin_amdgcn_mfma_f32_16x16x32_f16(af[mi], bf[ni], acc[mi][ni], 0, 0, 0);

    asm volatile("" ::: "memory");           // fence: no LDS read sinks below
    __builtin_amdgcn_s_barrier();            // buf[cur] free to overwrite next iter
  }

  // C/D layout: col = lane&15, row = quad*4 + reg
  if (role == 0) {
#pragma unroll
    for (int mi = 0; mi < 4; ++mi)
#pragma unroll
      for (int r = 0; r < 4; ++r) {
        const int row = m0 + wm + mi * 16 + quad * 4 + r;
#pragma unroll
        for (int ni = 0; ni < 4; ++ni) {
          const int col = n0 + wn + ni * 16 + lrow;
          const size_t idx = (size_t)row * HDIM + col;
          const float P = acc[mi][ni][r];
          const float vv = v[idx], ii = cur_in[idx], rr = rho[idx];
          const float vd = vv + 0.1f * (ii - vv) + P;
          float zo, vo, ro;
          if (rr > 0.0f) {  // refractory: hold v, suppress spike
            zo = 0.0f; vo = vv; ro = fmaxf(rr - 1.0f, 0.0f);
          } else {
            const bool zs = vd > 1.0f;
            zo = zs ? 1.0f : 0.0f;
            vo = zs ? 0.0f : vd;
            ro = zs ? 5.0f : fmaxf(rr, 0.0f);
            if (fabsf(vd - 1.0f) < MARGIN) {
              // block-local flag list; overflow (statistically never, ~75/block
              // expected) spills to the global list for the sweep kernel
              unsigned p = atomicAdd(&s_cnt, 1u);
              if (p < FLAG_LDS_CAP) s_idx[p] = (unsigned)idx;
              else {
                unsigned q = atomicAdd(flag_cnt, 1u);
                if (q < flag_cap) flag_list[q] = (unsigned)idx;
              }
            }
          }
          z_out[idx] = zo; v_out[idx] = vo; rho_out[idx] = ro;
        }
      }
    __syncthreads();                         // all flags in LDS; epilogue stores done
    // In-block fixup: this block owns every flagged idx (its own tile), so no
    // cross-block ordering is needed. Runs while role-1 blocks still compute.
    unsigned n = s_cnt;
    if (n > FLAG_LDS_CAP) n = FLAG_LDS_CAP;
    for (unsigned u = wave; u < n; u += 4)
      fixup_one(s_idx[u], v, cur_in, rho, gB ? nullptr : nullptr, z_out, v_out,
                rho_out, lane);  // placeholder never taken (see real call below)
  } else {
#pragma unroll
    for (int mi = 0; mi < 4; ++mi)
#pragma unroll
      for (int r = 0; r < 4; ++r) {
        const int row = m0 + wm + mi * 16 + quad * 4 + r;
#pragma unroll
        for (int ni = 0; ni < 4; ++ni) {
          const int col = n0 + wn + ni * 16 + lrow;
          const size_t idx = (size_t)row * HDIM + col;
          const float ii = cur_in[idx];
          i_out[idx] = (ii - 0.2f * ii) + acc[mi][ni][r];  // i_decayed + inp@Wi^T + z@Wr^T
        }
      }
  }
}

// NOTE: fixup_one needs the fp32 g matrix, which k_gemm doesn't receive in the
// template arg list above. Specialized wrapper kernel passes it explicitly.
template <typename T>
__global__ __launch_bounds__(256, 4)
void k_gemm_fx(const T* vA, const T* inpA, const T* zA,
               const T* gB, const T* WiB, const T* WrB,
               const float* v, const float* cur_in, const float* rho,
               const float* g32,
               float* z_out, float* v_out, float* rho_out, float* i_out,
               unsigned* flag_cnt, unsigned* flag_list, unsigned flag_cap) {
  __shared__ T As[2][BM * BK];
  __shared__ T Bs[2][BN * BK];
  __shared__ unsigned s_cnt;
  __shared__ unsigned s_idx[FLAG_LDS_CAP];
  const int t = threadIdx.x;
  const int bid = blockIdx.x;
  const int x = bid & 7;
  const int j = bid >> 3;
  const int role = (j >> 5) & 1;
  const int jj = (j & 31) | ((j >> 6) << 5);
  const int mg = x & 3, ng = x >> 2;
  const int m0 = (mg * 8 + (jj >> 3)) * BM;
  const int n0 = (ng * 8 + (jj & 7)) * BN;

  const int wave = t >> 6, lane = t & 63;
  const int wm = (wave >> 1) * 64, wn = (wave & 1) * 64;
  const int lrow = lane & 15, quad = lane >> 4;

  const int kmax = role ? 2 * KIN : KIN;
  const int NT = kmax / BK;

  auto pick = [&](int k0, const T*& Ap, const T*& Bp) {
    if (role == 0)      { Ap = vA;   Bp = gB;  }
    else if (k0 < KIN)  { Ap = inpA; Bp = WiB; }
    else                { Ap = zA;   Bp = WrB; }
  };

  {
    const T *Ap, *Bp;
    pick(0, Ap, Bp);
    stage(Ap, KIN, m0, 0, As[0], t);
    stage(Bp, KIN, n0, 0, Bs[0], t);
  }
  if (t == 0) s_cnt = 0;

  f32x4 acc[4][4] = {};
#pragma unroll 2
  for (int it = 0; it < NT; ++it) {
    const int cur = it & 1;
    if (it + 1 < NT) {
      const int k0n = (it + 1) * BK;
      const T *Ap, *Bp;
      pick(k0n, Ap, Bp);
      const int kl = k0n & (KIN - 1);
      stage(Ap, KIN, m0, kl, As[cur ^ 1], t);
      stage(Bp, KIN, n0, kl, Bs[cur ^ 1], t);
      if constexpr (sizeof(T) == 2)
        asm volatile("s_waitcnt vmcnt(4)" ::: "memory");
      else
        asm volatile("s_waitcnt vmcnt(8)" ::: "memory");
    } else {
      asm volatile("s_waitcnt vmcnt(0)" ::: "memory");
    }
    __builtin_amdgcn_s_barrier();
    asm volatile("" ::: "memory");

    f16x8 af[4], bf[4];
#pragma unroll
    for (int mi = 0; mi < 4; ++mi) af[mi] = read_frag(As[cur], wm + mi * 16 + lrow, quad);
#pragma unroll
    for (int ni = 0; ni < 4; ++ni) bf[ni] = read_frag(Bs[cur], wn + ni * 16 + lrow, quad);
#pragma unroll
    for (int mi = 0; mi < 4; ++mi)
#pragma unroll
      for (int ni = 0; ni < 4; ++ni)
        acc[mi][ni] =
            __builtin_amdgcn_mfma_f32_16x16x32_f16(af[mi], bf[ni], acc[mi][ni], 0, 0, 0);

    asm volatile("" ::: "memory");
    __builtin_amdgcn_s_barrier();
  }

  if (role == 0) {
#pragma unroll
    for (int mi = 0; mi < 4; ++mi)
#pragma unroll
      for (int r = 0; r < 4; ++r) {
        const int row = m0 + wm + mi * 16 + quad * 4 + r;
#pragma unroll
        for (int ni = 0; ni < 4; ++ni) {
          const int col = n0 + wn + ni * 16 + lrow;
          const size_t idx = (size_t)row * HDIM + col;
          const float P = acc[mi][ni][r];
          const float vv = v[idx], ii = cur_in[idx], rr = rho[idx];
          const float vd = vv + 0.1f * (ii - vv) + P;
          float zo, vo, ro;
          if (rr > 0.0f) {
            zo = 0.0f; vo = vv; ro = fmaxf(rr - 1.0f, 0.0f);
          } else {
            const bool zs = vd > 1.0f;
            zo = zs ? 1.0f : 0.0f;
            vo = zs ? 0.0f : vd;
            ro = zs ? 5.0f : fmaxf(rr, 0.0f);
            if (fabsf(vd - 1.0f) < MARGIN) {
              unsigned p = atomicAdd(&s_cnt, 1u);
              if (p < FLAG_LDS_CAP) s_idx[p] = (unsigned)idx;
              else {
                unsigned q = atomicAdd(flag_cnt, 1u);
                if (q < flag_cap) flag_list[q] = (unsigned)idx;
              }
            }
          }
          z_out[idx] = zo; v_out[idx] = vo; rho_out[idx] = ro;
        }
      }
    __syncthreads();                         // flags complete; epilogue stores done
    unsigned n = s_cnt;
    if (n > FLAG_LDS_CAP) n = FLAG_LDS_CAP;
    for (unsigned u = wave; u < n; u += 4)   // 4 waves sweep the block's own flags
      fixup_one(s_idx[u], v, cur_in, rho, g32, z_out, v_out, rho_out, lane);
  } else {
#pragma unroll
    for (int mi = 0; mi < 4; ++mi)
#pragma unroll
      for (int r = 0; r < 4; ++r) {
        const int row = m0 + wm + mi * 16 + quad * 4 + r;
#pragma unroll
        for (int ni = 0; ni < 4; ++ni) {
          const int col = n0 + wn + ni * 16 + lrow;
          const size_t idx = (size_t)row * HDIM + col;
          const float ii = cur_in[idx];
          i_out[idx] = (ii - 0.2f * ii) + acc[mi][ni][r];
        }
      }
  }
}

// ---- fp32 -> f16 cast of all six GEMM operands into ws; zero flag counter --------
__global__ void k_cast(const float* __restrict__ v, const float* __restrict__ inp,
                       const float* __restrict__ z, const float* __restrict__ g,
                       const float* __restrict__ Wi, const float* __restrict__ Wr,
                       _Float16* __restrict__ dst, unsigned* __restrict__ flag_cnt) {
  if (blockIdx.x == 0 && threadIdx.x == 0) *flag_cnt = 0;
  const size_t NA = (size_t)BATCH * HDIM, NB = (size_t)HDIM * HDIM;
  const size_t TOT = (3 * NA + 3 * NB) / 8;
  const size_t w = (size_t)blockIdx.x * blockDim.x + threadIdx.x;
  if (w >= TOT) return;
  const size_t e = w * 8;
  const float* s; size_t off;
  if      (e < NA)          { s = v;   off = e; }
  else if (e < 2 * NA)      { s = inp; off = e - NA; }
  else if (e < 3 * NA)      { s = z;   off = e - 2 * NA; }
  else if (e < 3 * NA + NB) { s = g;   off = e - 3 * NA; }
  else if (e < 3 * NA + 2 * NB) { s = Wi; off = e - 3 * NA - NB; }
  else                      { s = Wr;  off = e - 3 * NA - 2 * NB; }
  const f32x4 a = *(const f32x4*)(s + off);
  const f32x4 b = *(const f32x4*)(s + off + 4);
  f16x8 o; h16x2 p;
  p = __builtin_amdgcn_cvt_pkrtz(a[0], a[1]); o[0] = (_Float16)p[0]; o[1] = (_Float16)p[1];
  p = __builtin_amdgcn_cvt_pkrtz(a[2], a[3]); o[2] = (_Float16)p[0]; o[3] = (_Float16)p[1];
  p = __builtin_amdgcn_cvt_pkrtz(b[0], b[1]); o[4] = (_Float16)p[0]; o[5] = (_Float16)p[1];
  p = __builtin_amdgcn_cvt_pkrtz(b[2], b[3]); o[6] = (_Float16)p[0]; o[7] = (_Float16)p[1];
  *(f16x8*)(dst + e) = o;
}

__global__ void k_zero_cnt(unsigned* p) { if (threadIdx.x == 0) p[0] = 0; }

// ---- overflow sweep: fp64 recompute of flags that spilled past the LDS list ------
__global__ __launch_bounds__(256, 2)
void k_fixup(const float* __restrict__ v, const float* __restrict__ cur,
             const float* __restrict__ rho, const float* __restrict__ g,
             float* __restrict__ z_out, float* __restrict__ v_out,
             float* __restrict__ rho_out,
             const unsigned* __restrict__ flag_cnt,
             const unsigned* __restrict__ flag_list, unsigned flag_cap) {
  unsigned n = *flag_cnt;
  if (n > flag_cap) n = flag_cap;
  const int lane = threadIdx.x & 63;
  const int nw = gridDim.x * 4;
  for (unsigned it = blockIdx.x * 4 + (threadIdx.x >> 6); it < n; it += nw) {
    const unsigned idx = flag_list[it];
    fixup_one(idx, v, cur, rho, g, z_out, v_out, rho_out, lane);
  }
}

extern "C" void kernel_launch(void* const* d_in, const int* in_sizes, int n_in,
                              void* d_out, int out_size, void* d_ws, size_t ws_size,
                              hipStream_t stream) {
  (void)in_sizes; (void)n_in; (void)out_size;
  const float* inp = (const float*)d_in[0];
  const float* z   = (const float*)d_in[1];
  const float* v   = (const float*)d_in[2];
  const float* cur = (const float*)d_in[3];
  const float* rho = (const float*)d_in[4];
  const float* Wi  = (const float*)d_in[5];
  const float* Wr  = (const float*)d_in[6];
  const float* g   = (const float*)d_in[7];

  float* out = (float*)d_out;
  const size_t NE = (size_t)BATCH * HDIM;
  float* z_out = out;
  float* v_out = out + NE;
  float* i_out = out + 2 * NE;
  float* rho_out = out + 3 * NE;

  const size_t NA = NE, NB = (size_t)HDIM * HDIM;
  const size_t F16_NEED = (3 * NA + 3 * NB) * sizeof(_Float16);  // ~72 MB
  const bool use16 = ws_size >= F16_NEED + (1u << 22);

  unsigned* flag_cnt =
      use16 ? (unsigned*)((char*)d_ws + F16_NEED) : (unsigned*)d_ws;
  unsigned* flag_list = flag_cnt + 4;
  unsigned flag_cap = 0;
  {
    const size_t used = (size_t)((char*)flag_list - (char*)d_ws);
    if (ws_size > used + 64) {
      size_t cap = (ws_size - used) / sizeof(unsigned);
      if (cap > (size_t)4 * 1024 * 1024) cap = (size_t)4 * 1024 * 1024;
      flag_cap = (unsigned)cap;
    }
  }

  if (use16) {
    _Float16* ws16 = (_Float16*)d_ws;
    const _Float16* vh   = ws16;
    const _Float16* inph = ws16 + NA;
    const _Float16* zh   = ws16 + 2 * NA;
    const _Float16* gh   = ws16 + 3 * NA;
    const _Float16* Wih  = ws16 + 3 * NA + NB;
    const _Float16* Wrh  = ws16 + 3 * NA + 2 * NB;
    const size_t TOT = (3 * NA + 3 * NB) / 8;
    k_cast<<<(unsigned)((TOT + 255) / 256), 256, 0, stream>>>(v, inp, z, g, Wi, Wr,
                                                              ws16, flag_cnt);
    k_gemm_fx<_Float16><<<1024, 256, 0, stream>>>(vh, inph, zh, gh, Wih, Wrh,
                                                  v, cur, rho, g,
                                                  z_out, v_out, rho_out, i_out,
                                                  flag_cnt, flag_list, flag_cap);
  } else {
    k_zero_cnt<<<1, 64, 0, stream>>>(flag_cnt);
    k_gemm_fx<float><<<1024, 256, 0, stream>>>(v, inp, z, g, Wi, Wr,
                                               v, cur, rho, g,
                                               z_out, v_out, rho_out, i_out,
                                               flag_cnt, flag_list, flag_cap);
  }

  // overflow-only sweep (n expected ~0; small grid keeps it a few us)
  k_fixup<<<64, 256, 0, stream>>>(v, cur, rho, g, z_out, v_out, rho_out,
                                  flag_cnt, flag_list, flag_cap);
}